// Round 4
// baseline (762.491 us; speedup 1.0000x reference)
//
#include <hip/hip_runtime.h>

typedef unsigned short u16;
typedef float f32x4 __attribute__((ext_vector_type(4)));
typedef short bf16x8 __attribute__((ext_vector_type(8)));
typedef unsigned short u16x8 __attribute__((ext_vector_type(8)));

#define KD 768
#define NKT 24   // 768 / BK32

__device__ __forceinline__ float bf2f(u16 u) {
    union { unsigned i; float f; } v; v.i = ((unsigned)u) << 16; return v.f;
}
__device__ __forceinline__ u16 f2bf(float f) {
    union { float f; unsigned u; } x; x.f = f;
    unsigned r = x.u + 0x7fffu + ((x.u >> 16) & 1u);
    return (u16)(r >> 16);
}
__device__ __forceinline__ void async16(const void* g, void* l) {
    __builtin_amdgcn_global_load_lds((const __attribute__((address_space(1))) void*)g,
                                     (__attribute__((address_space(3))) void*)l, 16, 0, 0);
}

// ---- transpose+convert weights via LDS tiles: Wt[m][n][k] = bf16(W_m[k][n]) ----
__global__ __launch_bounds__(256) void conv_w(const float* __restrict__ W_emb,
                                              const float* __restrict__ gat_W,
                                              const float* __restrict__ W_out,
                                              u16* __restrict__ Wt)
{
    __shared__ float lds[64][65];
    const int m  = blockIdx.x / 144;
    const int r  = blockIdx.x % 144;
    const int tr = r / 12;
    const int tc = r % 12;
    const float* src = (m == 0) ? W_emb : (m <= 3) ? (gat_W + (size_t)(m - 1) * 589824) : W_out;
    const int c  = threadIdx.x & 63;
    const int w4 = threadIdx.x >> 6;
    #pragma unroll
    for (int i = 0; i < 16; ++i) {
        int kk = i * 4 + w4;
        lds[kk][c] = src[(size_t)(tr * 64 + kk) * 768 + tc * 64 + c];
    }
    __syncthreads();
    u16* dst = Wt + (size_t)m * 589824;
    #pragma unroll
    for (int i = 0; i < 16; ++i) {
        int nn = i * 4 + w4;
        dst[(size_t)(tc * 64 + nn) * 768 + tr * 64 + c] = f2bf(lds[c][nn]);
    }
}

// ---- fp32 -> bf16 bulk convert ----
__global__ __launch_bounds__(256) void conv_x(const float4* __restrict__ in,
                                              u16* __restrict__ outp, int n4)
{
    for (int i = blockIdx.x * 256 + threadIdx.x; i < n4; i += gridDim.x * 256) {
        float4 v = in[i];
        union { u16 s[4]; uint2 u; } o;
        o.s[0] = f2bf(v.x); o.s[1] = f2bf(v.y); o.s[2] = f2bf(v.z); o.s[3] = f2bf(v.w);
        ((uint2*)outp)[i] = o.u;
    }
}

// ---- deep-pipelined bf16 GEMM: C[m][n] = sum_k A[m][k]*Bt[n][k] (+bias) ----
// 256x256 tile, BK=32, 512 thr (8 waves, wave-tile 128x64), 4-deep circular
// LDS (4 x 32KB), counted vmcnt(8), 1 barrier/K-tile, T2 slot-swizzle, T5.
// grid 672 = 8 XCD chunks x 84 (M-major within chunk: 3 N-tiles consecutive).
template<bool F32OUT>
__global__ __launch_bounds__(512) void gemm8(const u16* __restrict__ A,
                                             const u16* __restrict__ Bt,
                                             const float* __restrict__ bias,
                                             void* __restrict__ Cout)
{
    extern __shared__ u16 lds[];   // 131072 B = 4 slots x (A 8192 u16 | B 8192 u16)
    const int tid  = threadIdx.x;
    const int lane = tid & 63;
    const int wid  = tid >> 6;
    const int wm   = (wid >> 2) * 128;   // wave M block (2)
    const int wn   = (wid & 3) * 64;     // wave N block (4)
    const int wg = blockIdx.x;
    const int id = (wg & 7) * 84 + (wg >> 3);
    const int tm = (id / 3) * 256;
    const int tn = (id % 3) * 256;

    // --- staging constants: thread writes physical (row = i*128 + tid/4, p = tid&3)
    // physical slot p holds logical slot s = (p - (row>>1)) & 3
    const int q  = tid >> 2;
    const int sS = ((tid & 3) - ((tid >> 3) & 3)) & 3;
    const u16* aS0 = A  + (size_t)(tm + q)       * KD + sS * 8;
    const u16* aS1 = A  + (size_t)(tm + 128 + q) * KD + sS * 8;
    const u16* bS0 = Bt + (size_t)(tn + q)       * KD + sS * 8;
    const u16* bS1 = Bt + (size_t)(tn + 128 + q) * KD + sS * 8;
    const int wb16 = (tid & ~63) * 8;    // wave base within an 8KB issue region (u16)

    #define STAGE(t) { const int sl = ((t) & 3) * 16384; const int kb = (t) * 32;   \
        async16(aS0 + kb, &lds[sl +         wb16]);                                  \
        async16(aS1 + kb, &lds[sl +  4096 + wb16]);                                  \
        async16(bS0 + kb, &lds[sl +  8192 + wb16]);                                  \
        async16(bS1 + kb, &lds[sl + 12288 + wb16]); }

    // --- read constants: logical s = lane>>4 at row -> physical p = (s + (row>>1))&3
    const int lr  = lane & 15;
    const int lsl = lane >> 4;
    const int p   = (lsl + (lr >> 1)) & 3;
    const int offA = (wm + lr) * 32 + p * 8;   // + mf*512
    const int offB = (wn + lr) * 32 + p * 8;   // + nf*512

    f32x4 acc[8][4] = {};

    STAGE(0); STAGE(1); STAGE(2);

    #pragma unroll 1
    for (int t = 0; t < NKT; ++t) {
        if (t < NKT - 2)       asm volatile("s_waitcnt vmcnt(8)" ::: "memory");
        else if (t == NKT - 2) asm volatile("s_waitcnt vmcnt(4)" ::: "memory");
        else                   asm volatile("s_waitcnt vmcnt(0)" ::: "memory");
        __builtin_amdgcn_s_barrier();
        asm volatile("" ::: "memory");
        if (t + 3 < NKT) STAGE(t + 3);
        const u16* As = &lds[(t & 3) * 16384];
        const u16* Bs = As + 8192;
        bf16x8 bf[4];
        #pragma unroll
        for (int nf = 0; nf < 4; ++nf)
            bf[nf] = *(const bf16x8*)&Bs[offB + nf * 512];
        __builtin_amdgcn_s_setprio(1);
        #pragma unroll
        for (int mf = 0; mf < 8; ++mf) {
            bf16x8 af = *(const bf16x8*)&As[offA + mf * 512];
            #pragma unroll
            for (int nf = 0; nf < 4; ++nf)
                acc[mf][nf] = __builtin_amdgcn_mfma_f32_16x16x32_bf16(
                    af, bf[nf], acc[mf][nf], 0, 0, 0);
        }
        __builtin_amdgcn_s_setprio(0);
    }
    #undef STAGE

    // epilogue: C/D layout col=lane&15, row=(lane>>4)*4+reg
    const int lr4 = lsl << 2;
    #pragma unroll
    for (int nf = 0; nf < 4; ++nf) {
        int col = tn + wn + nf * 16 + lr;
        float bv = bias ? bias[col] : 0.0f;
        #pragma unroll
        for (int mf = 0; mf < 8; ++mf) {
            int rowb = tm + wm + mf * 16 + lr4;
            #pragma unroll
            for (int r = 0; r < 4; ++r) {
                float v = acc[mf][nf][r] + bv;
                if (F32OUT)
                    ((float*)Cout)[(size_t)(rowb + r) * 768 + col] = v;
                else
                    ((u16*)Cout)[(size_t)(rowb + r) * 768 + col] = f2bf(v);
            }
        }
    }
}

// ---- fused GAT attention per batch: ei/ej from staged Wh, softmax, mix, ELU ----
// LDS-staged (safe when Xout aliases Wh).
template<bool ELU>
__global__ __launch_bounds__(256) void gat_mix(const u16* __restrict__ Wh,
                                               const float* __restrict__ adj,
                                               const float* __restrict__ avec,
                                               float* __restrict__ attn_out,
                                               u16* __restrict__ Xout)
{
    __shared__ u16 wh[14 * 768];
    __shared__ float s_ei[14], s_ej[14];
    __shared__ float s_attn[196];
    const int b = blockIdx.x;
    const int tid = threadIdx.x;
    const int lane = tid & 63, wave = tid >> 6;
    const u16* whb = Wh + (size_t)b * 10752;

    for (int c = tid; c < 1344; c += 256)
        ((uint4*)wh)[c] = ((const uint4*)whb)[c];
    __syncthreads();

    // ei[i] = dot(Wh[i,:], a_i); ej[i] = dot(Wh[i,:], a_j); vectorized, wave per row
    for (int i = wave; i < 14; i += 4) {
        float ai = 0.f, aj = 0.f;
        {
            u16x8 v = *(const u16x8*)&wh[i * 768 + lane * 8];
            float4 x0 = *(const float4*)&avec[lane * 8];
            float4 x1 = *(const float4*)&avec[lane * 8 + 4];
            float4 y0 = *(const float4*)&avec[768 + lane * 8];
            float4 y1 = *(const float4*)&avec[768 + lane * 8 + 4];
            float w0 = bf2f(v[0]), w1 = bf2f(v[1]), w2 = bf2f(v[2]), w3 = bf2f(v[3]);
            float w4 = bf2f(v[4]), w5 = bf2f(v[5]), w6 = bf2f(v[6]), w7 = bf2f(v[7]);
            ai += w0*x0.x + w1*x0.y + w2*x0.z + w3*x0.w + w4*x1.x + w5*x1.y + w6*x1.z + w7*x1.w;
            aj += w0*y0.x + w1*y0.y + w2*y0.z + w3*y0.w + w4*y1.x + w5*y1.y + w6*y1.z + w7*y1.w;
        }
        if (lane < 32) {
            int d = 512 + lane * 8;
            u16x8 v = *(const u16x8*)&wh[i * 768 + d];
            float4 x0 = *(const float4*)&avec[d];
            float4 x1 = *(const float4*)&avec[d + 4];
            float4 y0 = *(const float4*)&avec[768 + d];
            float4 y1 = *(const float4*)&avec[768 + d + 4];
            float w0 = bf2f(v[0]), w1 = bf2f(v[1]), w2 = bf2f(v[2]), w3 = bf2f(v[3]);
            float w4 = bf2f(v[4]), w5 = bf2f(v[5]), w6 = bf2f(v[6]), w7 = bf2f(v[7]);
            ai += w0*x0.x + w1*x0.y + w2*x0.z + w3*x0.w + w4*x1.x + w5*x1.y + w6*x1.z + w7*x1.w;
            aj += w0*y0.x + w1*y0.y + w2*y0.z + w3*y0.w + w4*y1.x + w5*y1.y + w6*y1.z + w7*y1.w;
        }
        #pragma unroll
        for (int off = 32; off > 0; off >>= 1) {
            ai += __shfl_down(ai, off);
            aj += __shfl_down(aj, off);
        }
        if (lane == 0) { s_ei[i] = ai; s_ej[i] = aj; }
    }
    __syncthreads();

    // masked softmax over j per row i (N=14, fp32)
    if (tid < 14) {
        const int i = tid;
        float e[14];
        float mx = -3.0e38f;
        #pragma unroll
        for (int j = 0; j < 14; ++j) {
            float ev = (adj[(size_t)b * 196 + i * 14 + j] > 0.f) ? (s_ei[i] + s_ej[j]) : -1.0e30f;
            e[j] = ev; mx = fmaxf(mx, ev);
        }
        float sum = 0.f;
        #pragma unroll
        for (int j = 0; j < 14; ++j) { float pp = __expf(e[j] - mx); e[j] = pp; sum += pp; }
        float inv = 1.0f / sum;
        #pragma unroll
        for (int j = 0; j < 14; ++j) s_attn[i * 14 + j] = e[j] * inv;
    }
    __syncthreads();

    if (tid < 196) attn_out[(size_t)b * 196 + tid] = s_attn[tid];

    // mix: h[i,d] = sum_j attn[i,j]*Wh[j,d]; opt ELU; write bf16 (16 elems/item)
    for (int pp = tid; pp < 14 * 48; pp += 256) {
        const int i  = pp / 48;
        const int d0 = (pp % 48) * 16;
        float acc[16] = {};
        #pragma unroll
        for (int j = 0; j < 14; ++j) {
            float aw = s_attn[i * 14 + j];
            u16x8 wv0 = *(const u16x8*)&wh[j * 768 + d0];
            u16x8 wv1 = *(const u16x8*)&wh[j * 768 + d0 + 8];
            #pragma unroll
            for (int qq = 0; qq < 8; ++qq) {
                acc[qq]     += aw * bf2f(wv0[qq]);
                acc[8 + qq] += aw * bf2f(wv1[qq]);
            }
        }
        union { u16 s[16]; uint4 u[2]; } o;
        #pragma unroll
        for (int qq = 0; qq < 16; ++qq) {
            float v = acc[qq];
            if (ELU && v < 0.f) v = __expf(v) - 1.0f;
            o.s[qq] = f2bf(v);
        }
        *(uint4*)&Xout[(size_t)b * 10752 + i * 768 + d0]     = o.u[0];
        *(uint4*)&Xout[(size_t)b * 10752 + i * 768 + d0 + 8] = o.u[1];
    }
}

extern "C" void kernel_launch(void* const* d_in, const int* in_sizes, int n_in,
                              void* d_out, int out_size, void* d_ws, size_t ws_size,
                              hipStream_t stream)
{
    const float* features = (const float*)d_in[0];
    const float* adj      = (const float*)d_in[1];
    const float* W_emb    = (const float*)d_in[2];
    const float* b_emb    = (const float*)d_in[3];
    const float* gat_W    = (const float*)d_in[4];
    const float* gat_a    = (const float*)d_in[5];
    const float* W_out    = (const float*)d_in[6];
    const float* b_out    = (const float*)d_in[7];
    float* out = (float*)d_out;

    // ws: Wh (bf16 57344x768) | Wt (5 transposed bf16 mats)
    u16* Wh = (u16*)d_ws;
    u16* Wt = Wh + 44040192;
    // out-region as two bf16 x ping-pong halves until the final GEMM
    u16* H0 = (u16*)d_out;
    u16* H1 = H0 + 44040192;
    float* attn0 = out + 44040192;
    float* attn1 = attn0 + 802816;
    float* attn2 = attn1 + 802816;

    conv_w<<<dim3(720), 256, 0, stream>>>(W_emb, gat_W, W_out, Wt);
    conv_x<<<dim3(4096), 256, 0, stream>>>((const float4*)features, H0, 11010048);

    dim3 gg(672);
    const size_t LSZ = 131072;
    // x0 = features @ W_emb + b_emb
    gemm8<false><<<gg, 512, LSZ, stream>>>(H0, Wt, b_emb, H1);
    // layer 0
    gemm8<false><<<gg, 512, LSZ, stream>>>(H1, Wt + 589824, nullptr, Wh);
    gat_mix<true><<<dim3(4096), 256, 0, stream>>>(Wh, adj, gat_a, attn0, H0);
    // layer 1
    gemm8<false><<<gg, 512, LSZ, stream>>>(H0, Wt + 2 * 589824, nullptr, Wh);
    gat_mix<true><<<dim3(4096), 256, 0, stream>>>(Wh, adj, gat_a + 1536, attn1, H1);
    // layer 2 (no ELU; x3 in-place over Wh -> staged kernel is safe)
    gemm8<false><<<gg, 512, LSZ, stream>>>(H1, Wt + 3 * 589824, nullptr, Wh);
    gat_mix<false><<<dim3(4096), 256, 0, stream>>>(Wh, adj, gat_a + 3072, attn2, Wh);
    // out = x3 @ W_out + b_out (fp32)
    gemm8<true><<<gg, 512, LSZ, stream>>>(Wh, Wt + 4 * 589824, b_out, (void*)out);
}

// Round 5
// 742.028 us; speedup vs baseline: 1.0276x; 1.0276x over previous
//
#include <hip/hip_runtime.h>

typedef unsigned short u16;
typedef float f32x4 __attribute__((ext_vector_type(4)));
typedef short bf16x8 __attribute__((ext_vector_type(8)));
typedef unsigned short u16x8 __attribute__((ext_vector_type(8)));

#define ND 768
#define KD 768

__device__ __forceinline__ float bf2f(u16 u) {
    union { unsigned i; float f; } v; v.i = ((unsigned)u) << 16; return v.f;
}
__device__ __forceinline__ u16 f2bf(float f) {
    union { float f; unsigned u; } x; x.f = f;
    unsigned r = x.u + 0x7fffu + ((x.u >> 16) & 1u);
    return (u16)(r >> 16);
}
__device__ __forceinline__ void async16(const void* g, void* l) {
    __builtin_amdgcn_global_load_lds((const __attribute__((address_space(1))) void*)g,
                                     (__attribute__((address_space(3))) void*)l, 16, 0, 0);
}

// ---- transpose+convert weights via LDS tiles: Wt[m][n][k] = bf16(W_m[k][n]) ----
__global__ __launch_bounds__(256) void conv_w(const float* __restrict__ W_emb,
                                              const float* __restrict__ gat_W,
                                              const float* __restrict__ W_out,
                                              u16* __restrict__ Wt)
{
    __shared__ float lds[64][65];
    const int m  = blockIdx.x / 144;
    const int r  = blockIdx.x % 144;
    const int tr = r / 12;
    const int tc = r % 12;
    const float* src = (m == 0) ? W_emb : (m <= 3) ? (gat_W + (size_t)(m - 1) * 589824) : W_out;
    const int c  = threadIdx.x & 63;
    const int w4 = threadIdx.x >> 6;
    #pragma unroll
    for (int i = 0; i < 16; ++i) {
        int kk = i * 4 + w4;
        lds[kk][c] = src[(size_t)(tr * 64 + kk) * 768 + tc * 64 + c];
    }
    __syncthreads();
    u16* dst = Wt + (size_t)m * 589824;
    #pragma unroll
    for (int i = 0; i < 16; ++i) {
        int nn = i * 4 + w4;
        dst[(size_t)(tc * 64 + nn) * 768 + tr * 64 + c] = f2bf(lds[c][nn]);
    }
}

// ---- fp32 -> bf16 bulk convert ----
__global__ __launch_bounds__(256) void conv_x(const float4* __restrict__ in,
                                              u16* __restrict__ outp, int n4)
{
    for (int i = blockIdx.x * 256 + threadIdx.x; i < n4; i += gridDim.x * 256) {
        float4 v = in[i];
        union { u16 s[4]; uint2 u; } o;
        o.s[0] = f2bf(v.x); o.s[1] = f2bf(v.y); o.s[2] = f2bf(v.z); o.s[3] = f2bf(v.w);
        ((uint2*)outp)[i] = o.u;
    }
}

// ---- m97-style bf16 GEMM (verified 77us on this problem, R1 exact) ----
// C[m][n] = sum_k A[m][k] * Bt[n][k] (+bias). grid 2688 XCD-chunk-swizzled.
template<bool F32OUT>
__global__ __launch_bounds__(256) void gemm_bt(const u16* __restrict__ A,
                                               const u16* __restrict__ Bt,
                                               const float* __restrict__ bias,
                                               void* __restrict__ Cout)
{
    __shared__ u16 lA[128 * 32];
    __shared__ u16 lB[128 * 32];
    const int tid  = threadIdx.x;
    const int lane = tid & 63;
    const int wvb  = tid & ~63;              // wave*64
    const int wm   = ((tid >> 7) & 1) * 64;  // wave row block
    const int wn   = ((tid >> 6) & 1) * 64;  // wave col block
    // XCD-chunked bijective swizzle: 2688 = 8 * 336; col-blocks of one row
    // panel consecutive within one XCD chunk -> A panel L2-shared.
    const int wg = blockIdx.x;
    const int id = (wg & 7) * 336 + (wg >> 3);
    const int tn = (id % 6) * 128;
    const int tm = (id / 6) * 128;

    f32x4 acc[4][4] = {};

    const int lr = lane & 15;
    const int lk = (lane >> 4) << 3;

    for (int ks = 0; ks < KD / 32; ++ks) {
        const int k0 = ks * 32;
        #pragma unroll
        for (int it = 0; it < 2; ++it) {
            int c   = tid + it * 256;        // chunk id 0..511
            int row = c >> 2;                // 4 chunks of 8 bf16 per row (BK=32)
            int kc  = (c & 3) << 3;
            async16(A + (size_t)(tm + row) * KD + (k0 + kc),
                    &lA[(size_t)(it * 256 + wvb) * 8]);
            async16(Bt + (size_t)(tn + row) * KD + (k0 + kc),
                    &lB[(size_t)(it * 256 + wvb) * 8]);
        }
        __syncthreads();   // drains vmcnt(0)

        bf16x8 af[4], bf[4];
        #pragma unroll
        for (int mi = 0; mi < 4; ++mi)
            af[mi] = *(const bf16x8*)&lA[(wm + mi * 16 + lr) * 32 + lk];
        #pragma unroll
        for (int ni = 0; ni < 4; ++ni)
            bf[ni] = *(const bf16x8*)&lB[(wn + ni * 16 + lr) * 32 + lk];
        #pragma unroll
        for (int mi = 0; mi < 4; ++mi)
            #pragma unroll
            for (int ni = 0; ni < 4; ++ni)
                acc[mi][ni] = __builtin_amdgcn_mfma_f32_16x16x32_bf16(
                    af[mi], bf[ni], acc[mi][ni], 0, 0, 0);
        __syncthreads();
    }

    // epilogue: C/D layout col=lane&15, row=(lane>>4)*4+reg
    const int lr4 = (lane >> 4) << 2;
    #pragma unroll
    for (int ni = 0; ni < 4; ++ni) {
        int col = tn + wn + ni * 16 + lr;
        float bv = bias ? bias[col] : 0.0f;
        #pragma unroll
        for (int mi = 0; mi < 4; ++mi) {
            int rowb = tm + wm + mi * 16 + lr4;
            #pragma unroll
            for (int r = 0; r < 4; ++r) {
                float v = acc[mi][ni][r] + bv;
                if (F32OUT)
                    ((float*)Cout)[(size_t)(rowb + r) * ND + col] = v;
                else
                    ((u16*)Cout)[(size_t)(rowb + r) * ND + col] = f2bf(v);
            }
        }
    }
}

// ---- fused GAT attention per batch: ei/ej from staged Wh, softmax, mix, ELU ----
// LDS-staged (safe when Xout aliases Wh).
template<bool ELU>
__global__ __launch_bounds__(256) void gat_mix(const u16* __restrict__ Wh,
                                               const float* __restrict__ adj,
                                               const float* __restrict__ avec,
                                               float* __restrict__ attn_out,
                                               u16* __restrict__ Xout)
{
    __shared__ u16 wh[14 * 768];
    __shared__ float s_ei[14], s_ej[14];
    __shared__ float s_attn[196];
    const int b = blockIdx.x;
    const int tid = threadIdx.x;
    const u16* whb = Wh + (size_t)b * 10752;

    for (int c = tid; c < 1344; c += 256)
        ((uint4*)wh)[c] = ((const uint4*)whb)[c];
    __syncthreads();

    // ei/ej: 14 rows x 16 lanes, each lane sums 6 chunks of 8, 4-step shuffle
    if (tid < 224) {
        const int i = tid >> 4, l = tid & 15;
        float ai = 0.f, aj = 0.f;
        #pragma unroll
        for (int c = 0; c < 6; ++c) {
            int d = c * 128 + l * 8;
            u16x8 v  = *(const u16x8*)&wh[i * 768 + d];
            float4 x0 = *(const float4*)&avec[d];
            float4 x1 = *(const float4*)&avec[d + 4];
            float4 y0 = *(const float4*)&avec[768 + d];
            float4 y1 = *(const float4*)&avec[768 + d + 4];
            float w0 = bf2f(v[0]), w1 = bf2f(v[1]), w2 = bf2f(v[2]), w3 = bf2f(v[3]);
            float w4 = bf2f(v[4]), w5 = bf2f(v[5]), w6 = bf2f(v[6]), w7 = bf2f(v[7]);
            ai += w0*x0.x + w1*x0.y + w2*x0.z + w3*x0.w + w4*x1.x + w5*x1.y + w6*x1.z + w7*x1.w;
            aj += w0*y0.x + w1*y0.y + w2*y0.z + w3*y0.w + w4*y1.x + w5*y1.y + w6*y1.z + w7*y1.w;
        }
        #pragma unroll
        for (int off = 8; off; off >>= 1) {
            ai += __shfl_xor(ai, off);
            aj += __shfl_xor(aj, off);
        }
        if (l == 0) { s_ei[i] = ai; s_ej[i] = aj; }
    }
    __syncthreads();

    // masked softmax over j per row i (N=14, fp32)
    if (tid < 14) {
        const int i = tid;
        float e[14];
        float mx = -3.0e38f;
        #pragma unroll
        for (int j = 0; j < 14; ++j) {
            float ev = (adj[(size_t)b * 196 + i * 14 + j] > 0.f) ? (s_ei[i] + s_ej[j]) : -1.0e30f;
            e[j] = ev; mx = fmaxf(mx, ev);
        }
        float sum = 0.f;
        #pragma unroll
        for (int j = 0; j < 14; ++j) { float pp = __expf(e[j] - mx); e[j] = pp; sum += pp; }
        float inv = 1.0f / sum;
        #pragma unroll
        for (int j = 0; j < 14; ++j) s_attn[i * 14 + j] = e[j] * inv;
    }
    __syncthreads();

    if (tid < 196) attn_out[(size_t)b * 196 + tid] = s_attn[tid];

    // mix: h[i,d] = sum_j attn[i,j]*Wh[j,d]; opt ELU; write bf16 (16 elems/item)
    for (int pp = tid; pp < 14 * 48; pp += 256) {
        const int i  = pp / 48;
        const int d0 = (pp % 48) * 16;
        float acc[16] = {};
        #pragma unroll
        for (int j = 0; j < 14; ++j) {
            float aw = s_attn[i * 14 + j];
            u16x8 wv0 = *(const u16x8*)&wh[j * 768 + d0];
            u16x8 wv1 = *(const u16x8*)&wh[j * 768 + d0 + 8];
            #pragma unroll
            for (int qq = 0; qq < 8; ++qq) {
                acc[qq]     += aw * bf2f(wv0[qq]);
                acc[8 + qq] += aw * bf2f(wv1[qq]);
            }
        }
        union { u16 s[16]; uint4 u[2]; } o;
        #pragma unroll
        for (int qq = 0; qq < 16; ++qq) {
            float v = acc[qq];
            if (ELU && v < 0.f) v = __expf(v) - 1.0f;
            o.s[qq] = f2bf(v);
        }
        *(uint4*)&Xout[(size_t)b * 10752 + i * 768 + d0]     = o.u[0];
        *(uint4*)&Xout[(size_t)b * 10752 + i * 768 + d0 + 8] = o.u[1];
    }
}

extern "C" void kernel_launch(void* const* d_in, const int* in_sizes, int n_in,
                              void* d_out, int out_size, void* d_ws, size_t ws_size,
                              hipStream_t stream)
{
    const float* features = (const float*)d_in[0];
    const float* adj      = (const float*)d_in[1];
    const float* W_emb    = (const float*)d_in[2];
    const float* b_emb    = (const float*)d_in[3];
    const float* gat_W    = (const float*)d_in[4];
    const float* gat_a    = (const float*)d_in[5];
    const float* W_out    = (const float*)d_in[6];
    const float* b_out    = (const float*)d_in[7];
    float* out = (float*)d_out;

    // ws: Wh (bf16 57344x768) | Wt (5 transposed bf16 mats)
    u16* Wh = (u16*)d_ws;
    u16* Wt = Wh + 44040192;
    // out-region as two bf16 x ping-pong halves until the final GEMM
    u16* H0 = (u16*)d_out;
    u16* H1 = H0 + 44040192;
    float* attn0 = out + 44040192;
    float* attn1 = attn0 + 802816;
    float* attn2 = attn1 + 802816;

    conv_w<<<dim3(720), 256, 0, stream>>>(W_emb, gat_W, W_out, Wt);
    conv_x<<<dim3(4096), 256, 0, stream>>>((const float4*)features, H0, 11010048);

    dim3 gg(2688);
    // x0 = features @ W_emb + b_emb
    gemm_bt<false><<<gg, 256, 0, stream>>>(H0, Wt, b_emb, H1);
    // layer 0
    gemm_bt<false><<<gg, 256, 0, stream>>>(H1, Wt + 589824, nullptr, Wh);
    gat_mix<true><<<dim3(4096), 256, 0, stream>>>(Wh, adj, gat_a, attn0, H0);
    // layer 1
    gemm_bt<false><<<gg, 256, 0, stream>>>(H0, Wt + 2 * 589824, nullptr, Wh);
    gat_mix<true><<<dim3(4096), 256, 0, stream>>>(Wh, adj, gat_a + 1536, attn1, H1);
    // layer 2 (no ELU; x3 in-place over Wh -> staged kernel is safe)
    gemm_bt<false><<<gg, 256, 0, stream>>>(H1, Wt + 3 * 589824, nullptr, Wh);
    gat_mix<false><<<dim3(4096), 256, 0, stream>>>(Wh, adj, gat_a + 3072, attn2, Wh);
    // out = x3 @ W_out + b_out (fp32)
    gemm_bt<true><<<gg, 256, 0, stream>>>(Wh, Wt + 4 * 589824, b_out, (void*)out);
}

// Round 6
// 731.978 us; speedup vs baseline: 1.0417x; 1.0137x over previous
//
#include <hip/hip_runtime.h>

typedef unsigned short u16;
typedef float f32x4 __attribute__((ext_vector_type(4)));
typedef short bf16x8 __attribute__((ext_vector_type(8)));
typedef unsigned short u16x8 __attribute__((ext_vector_type(8)));

#define ND 768
#define KD 768

__device__ __forceinline__ float bf2f(u16 u) {
    union { unsigned i; float f; } v; v.i = ((unsigned)u) << 16; return v.f;
}
__device__ __forceinline__ u16 f2bf(float f) {
    union { float f; unsigned u; } x; x.f = f;
    unsigned r = x.u + 0x7fffu + ((x.u >> 16) & 1u);
    return (u16)(r >> 16);
}
__device__ __forceinline__ void async16(const void* g, void* l) {
    __builtin_amdgcn_global_load_lds((const __attribute__((address_space(1))) void*)g,
                                     (__attribute__((address_space(3))) void*)l, 16, 0, 0);
}

// ---- transpose+convert weights via LDS tiles: Wt[m][n][k] = bf16(W_m[k][n]) ----
__global__ __launch_bounds__(256) void conv_w(const float* __restrict__ W_emb,
                                              const float* __restrict__ gat_W,
                                              const float* __restrict__ W_out,
                                              u16* __restrict__ Wt)
{
    __shared__ float lds[64][65];
    const int m  = blockIdx.x / 144;
    const int r  = blockIdx.x % 144;
    const int tr = r / 12;
    const int tc = r % 12;
    const float* src = (m == 0) ? W_emb : (m <= 3) ? (gat_W + (size_t)(m - 1) * 589824) : W_out;
    const int c  = threadIdx.x & 63;
    const int w4 = threadIdx.x >> 6;
    #pragma unroll
    for (int i = 0; i < 16; ++i) {
        int kk = i * 4 + w4;
        lds[kk][c] = src[(size_t)(tr * 64 + kk) * 768 + tc * 64 + c];
    }
    __syncthreads();
    u16* dst = Wt + (size_t)m * 589824;
    #pragma unroll
    for (int i = 0; i < 16; ++i) {
        int nn = i * 4 + w4;
        dst[(size_t)(tc * 64 + nn) * 768 + tr * 64 + c] = f2bf(lds[c][nn]);
    }
}

// ---- fp32 -> bf16 bulk convert ----
__global__ __launch_bounds__(256) void conv_x(const float4* __restrict__ in,
                                              u16* __restrict__ outp, int n4)
{
    for (int i = blockIdx.x * 256 + threadIdx.x; i < n4; i += gridDim.x * 256) {
        float4 v = in[i];
        union { u16 s[4]; uint2 u; } o;
        o.s[0] = f2bf(v.x); o.s[1] = f2bf(v.y); o.s[2] = f2bf(v.z); o.s[3] = f2bf(v.w);
        ((uint2*)outp)[i] = o.u;
    }
}

// ---- m97-style bf16 GEMM + T2 slot-swizzle (conflict-free LDS reads) ----
// C[m][n] = sum_k A[m][k] * Bt[n][k] (+bias). grid 2688 XCD-chunk-swizzled.
// LDS 16B-chunk layout: physical slot p at row r holds logical k-chunk
// l = p ^ ((r>>1)&3). Staged via pre-swizzled GLOBAL source (linear LDS dest,
// rule #21); readers XOR the same involution.
template<bool F32OUT>
__global__ __launch_bounds__(256) void gemm_bt(const u16* __restrict__ A,
                                               const u16* __restrict__ Bt,
                                               const float* __restrict__ bias,
                                               void* __restrict__ Cout)
{
    __shared__ u16 lA[128 * 32];
    __shared__ u16 lB[128 * 32];
    const int tid  = threadIdx.x;
    const int lane = tid & 63;
    const int wvb  = tid & ~63;              // wave*64
    const int wm   = ((tid >> 7) & 1) * 64;  // wave row block
    const int wn   = ((tid >> 6) & 1) * 64;  // wave col block
    // XCD-chunked bijective swizzle: 2688 = 8 * 336
    const int wg = blockIdx.x;
    const int id = (wg & 7) * 336 + (wg >> 3);
    const int tn = (id % 6) * 128;
    const int tm = (id / 6) * 128;

    f32x4 acc[4][4] = {};

    const int lr = lane & 15;
    // read-side swizzle: logical slot = lane>>4, physical = l ^ ((row>>1)&3);
    // (row>>1)&3 == (lr>>1)&3 for all mi/ni since wm/wn/mi*16 are multiples of 8.
    const int lk = (((lane >> 4) ^ ((lr >> 1) & 3)) << 3);

    for (int ks = 0; ks < KD / 32; ++ks) {
        const int k0 = ks * 32;
        #pragma unroll
        for (int it = 0; it < 2; ++it) {
            int c   = tid + it * 256;        // chunk id 0..511
            int row = c >> 2;                // 4 chunks of 8 bf16 per row (BK=32)
            int kc  = (((c & 3) ^ ((c >> 3) & 3)) << 3);  // pre-swizzled source
            async16(A + (size_t)(tm + row) * KD + (k0 + kc),
                    &lA[(size_t)(it * 256 + wvb) * 8]);
            async16(Bt + (size_t)(tn + row) * KD + (k0 + kc),
                    &lB[(size_t)(it * 256 + wvb) * 8]);
        }
        __syncthreads();   // drains vmcnt(0)

        bf16x8 af[4], bf[4];
        #pragma unroll
        for (int mi = 0; mi < 4; ++mi)
            af[mi] = *(const bf16x8*)&lA[(wm + mi * 16 + lr) * 32 + lk];
        #pragma unroll
        for (int ni = 0; ni < 4; ++ni)
            bf[ni] = *(const bf16x8*)&lB[(wn + ni * 16 + lr) * 32 + lk];
        #pragma unroll
        for (int mi = 0; mi < 4; ++mi)
            #pragma unroll
            for (int ni = 0; ni < 4; ++ni)
                acc[mi][ni] = __builtin_amdgcn_mfma_f32_16x16x32_bf16(
                    af[mi], bf[ni], acc[mi][ni], 0, 0, 0);
        __syncthreads();
    }

    // epilogue: C/D layout col=lane&15, row=(lane>>4)*4+reg
    const int lr4 = (lane >> 4) << 2;
    #pragma unroll
    for (int ni = 0; ni < 4; ++ni) {
        int col = tn + wn + ni * 16 + lr;
        float bv = bias ? bias[col] : 0.0f;
        #pragma unroll
        for (int mi = 0; mi < 4; ++mi) {
            int rowb = tm + wm + mi * 16 + lr4;
            #pragma unroll
            for (int r = 0; r < 4; ++r) {
                float v = acc[mi][ni][r] + bv;
                if (F32OUT)
                    ((float*)Cout)[(size_t)(rowb + r) * ND + col] = v;
                else
                    ((u16*)Cout)[(size_t)(rowb + r) * ND + col] = f2bf(v);
            }
        }
    }
}

// ---- fused GAT attention per batch: ei/ej from staged Wh, softmax, mix, ELU ----
// LDS-staged (safe when Xout aliases Wh).
template<bool ELU>
__global__ __launch_bounds__(256) void gat_mix(const u16* __restrict__ Wh,
                                               const float* __restrict__ adj,
                                               const float* __restrict__ avec,
                                               float* __restrict__ attn_out,
                                               u16* __restrict__ Xout)
{
    __shared__ u16 wh[14 * 768];
    __shared__ float s_ei[14], s_ej[14];
    __shared__ float s_attn[196];
    const int b = blockIdx.x;
    const int tid = threadIdx.x;
    const u16* whb = Wh + (size_t)b * 10752;

    for (int c = tid; c < 1344; c += 256)
        ((uint4*)wh)[c] = ((const uint4*)whb)[c];
    __syncthreads();

    // ei/ej: 14 rows x 16 lanes, each lane sums 6 chunks of 8, 4-step shuffle
    if (tid < 224) {
        const int i = tid >> 4, l = tid & 15;
        float ai = 0.f, aj = 0.f;
        #pragma unroll
        for (int c = 0; c < 6; ++c) {
            int d = c * 128 + l * 8;
            u16x8 v  = *(const u16x8*)&wh[i * 768 + d];
            float4 x0 = *(const float4*)&avec[d];
            float4 x1 = *(const float4*)&avec[d + 4];
            float4 y0 = *(const float4*)&avec[768 + d];
            float4 y1 = *(const float4*)&avec[768 + d + 4];
            float w0 = bf2f(v[0]), w1 = bf2f(v[1]), w2 = bf2f(v[2]), w3 = bf2f(v[3]);
            float w4 = bf2f(v[4]), w5 = bf2f(v[5]), w6 = bf2f(v[6]), w7 = bf2f(v[7]);
            ai += w0*x0.x + w1*x0.y + w2*x0.z + w3*x0.w + w4*x1.x + w5*x1.y + w6*x1.z + w7*x1.w;
            aj += w0*y0.x + w1*y0.y + w2*y0.z + w3*y0.w + w4*y1.x + w5*y1.y + w6*y1.z + w7*y1.w;
        }
        #pragma unroll
        for (int off = 8; off; off >>= 1) {
            ai += __shfl_xor(ai, off);
            aj += __shfl_xor(aj, off);
        }
        if (l == 0) { s_ei[i] = ai; s_ej[i] = aj; }
    }
    __syncthreads();

    // masked softmax over j per row i (N=14, fp32)
    if (tid < 14) {
        const int i = tid;
        float e[14];
        float mx = -3.0e38f;
        #pragma unroll
        for (int j = 0; j < 14; ++j) {
            float ev = (adj[(size_t)b * 196 + i * 14 + j] > 0.f) ? (s_ei[i] + s_ej[j]) : -1.0e30f;
            e[j] = ev; mx = fmaxf(mx, ev);
        }
        float sum = 0.f;
        #pragma unroll
        for (int j = 0; j < 14; ++j) { float pp = __expf(e[j] - mx); e[j] = pp; sum += pp; }
        float inv = 1.0f / sum;
        #pragma unroll
        for (int j = 0; j < 14; ++j) s_attn[i * 14 + j] = e[j] * inv;
    }
    __syncthreads();

    if (tid < 196) attn_out[(size_t)b * 196 + tid] = s_attn[tid];

    // mix: h[i,d] = sum_j attn[i,j]*Wh[j,d]; opt ELU; write bf16 (16 elems/item)
    for (int pp = tid; pp < 14 * 48; pp += 256) {
        const int i  = pp / 48;
        const int d0 = (pp % 48) * 16;
        float acc[16] = {};
        #pragma unroll
        for (int j = 0; j < 14; ++j) {
            float aw = s_attn[i * 14 + j];
            u16x8 wv0 = *(const u16x8*)&wh[j * 768 + d0];
            u16x8 wv1 = *(const u16x8*)&wh[j * 768 + d0 + 8];
            #pragma unroll
            for (int qq = 0; qq < 8; ++qq) {
                acc[qq]     += aw * bf2f(wv0[qq]);
                acc[8 + qq] += aw * bf2f(wv1[qq]);
            }
        }
        union { u16 s[16]; uint4 u[2]; } o;
        #pragma unroll
        for (int qq = 0; qq < 16; ++qq) {
            float v = acc[qq];
            if (ELU && v < 0.f) v = __expf(v) - 1.0f;
            o.s[qq] = f2bf(v);
        }
        *(uint4*)&Xout[(size_t)b * 10752 + i * 768 + d0]     = o.u[0];
        *(uint4*)&Xout[(size_t)b * 10752 + i * 768 + d0 + 8] = o.u[1];
    }
}

extern "C" void kernel_launch(void* const* d_in, const int* in_sizes, int n_in,
                              void* d_out, int out_size, void* d_ws, size_t ws_size,
                              hipStream_t stream)
{
    const float* features = (const float*)d_in[0];
    const float* adj      = (const float*)d_in[1];
    const float* W_emb    = (const float*)d_in[2];
    const float* b_emb    = (const float*)d_in[3];
    const float* gat_W    = (const float*)d_in[4];
    const float* gat_a    = (const float*)d_in[5];
    const float* W_out    = (const float*)d_in[6];
    const float* b_out    = (const float*)d_in[7];
    float* out = (float*)d_out;

    // ws: Wh (bf16 57344x768) | Wt (5 transposed bf16 mats)
    u16* Wh = (u16*)d_ws;
    u16* Wt = Wh + 44040192;
    // out-region as two bf16 x ping-pong halves until the final GEMM
    u16* H0 = (u16*)d_out;
    u16* H1 = H0 + 44040192;
    float* attn0 = out + 44040192;
    float* attn1 = attn0 + 802816;
    float* attn2 = attn1 + 802816;

    conv_w<<<dim3(720), 256, 0, stream>>>(W_emb, gat_W, W_out, Wt);
    conv_x<<<dim3(4096), 256, 0, stream>>>((const float4*)features, H0, 11010048);

    dim3 gg(2688);
    // x0 = features @ W_emb + b_emb
    gemm_bt<false><<<gg, 256, 0, stream>>>(H0, Wt, b_emb, H1);
    // layer 0
    gemm_bt<false><<<gg, 256, 0, stream>>>(H1, Wt + 589824, nullptr, Wh);
    gat_mix<true><<<dim3(4096), 256, 0, stream>>>(Wh, adj, gat_a, attn0, H0);
    // layer 1
    gemm_bt<false><<<gg, 256, 0, stream>>>(H0, Wt + 2 * 589824, nullptr, Wh);
    gat_mix<true><<<dim3(4096), 256, 0, stream>>>(Wh, adj, gat_a + 1536, attn1, H1);
    // layer 2 (no ELU; x3 in-place over Wh -> staged kernel is safe)
    gemm_bt<false><<<gg, 256, 0, stream>>>(H1, Wt + 3 * 589824, nullptr, Wh);
    gat_mix<false><<<dim3(4096), 256, 0, stream>>>(Wh, adj, gat_a + 3072, attn2, Wh);
    // out = x3 @ W_out + b_out (fp32)
    gemm_bt<true><<<gg, 256, 0, stream>>>(Wh, Wt + 4 * 589824, b_out, (void*)out);
}

// Round 7
// 702.319 us; speedup vs baseline: 1.0857x; 1.0422x over previous
//
#include <hip/hip_runtime.h>

typedef unsigned short u16;
typedef float f32x4 __attribute__((ext_vector_type(4)));
typedef short bf16x8 __attribute__((ext_vector_type(8)));
typedef unsigned short u16x8 __attribute__((ext_vector_type(8)));

#define ND 768
#define KD 768

__device__ __forceinline__ float bf2f(u16 u) {
    union { unsigned i; float f; } v; v.i = ((unsigned)u) << 16; return v.f;
}
__device__ __forceinline__ u16 f2bf(float f) {
    union { float f; unsigned u; } x; x.f = f;
    unsigned r = x.u + 0x7fffu + ((x.u >> 16) & 1u);
    return (u16)(r >> 16);
}
__device__ __forceinline__ void async16(const void* g, void* l) {
    __builtin_amdgcn_global_load_lds((const __attribute__((address_space(1))) void*)g,
                                     (__attribute__((address_space(3))) void*)l, 16, 0, 0);
}

// ---- transpose+convert weights via LDS tiles: Wt[m][n][k] = bf16(W_m[k][n]) ----
__global__ __launch_bounds__(256) void conv_w(const float* __restrict__ W_emb,
                                              const float* __restrict__ gat_W,
                                              const float* __restrict__ W_out,
                                              u16* __restrict__ Wt)
{
    __shared__ float lds[64][65];
    const int m  = blockIdx.x / 144;
    const int r  = blockIdx.x % 144;
    const int tr = r / 12;
    const int tc = r % 12;
    const float* src = (m == 0) ? W_emb : (m <= 3) ? (gat_W + (size_t)(m - 1) * 589824) : W_out;
    const int c  = threadIdx.x & 63;
    const int w4 = threadIdx.x >> 6;
    #pragma unroll
    for (int i = 0; i < 16; ++i) {
        int kk = i * 4 + w4;
        lds[kk][c] = src[(size_t)(tr * 64 + kk) * 768 + tc * 64 + c];
    }
    __syncthreads();
    u16* dst = Wt + (size_t)m * 589824;
    #pragma unroll
    for (int i = 0; i < 16; ++i) {
        int nn = i * 4 + w4;
        dst[(size_t)(tc * 64 + nn) * 768 + tr * 64 + c] = f2bf(lds[c][nn]);
    }
}

// ---- fp32 -> bf16 bulk convert ----
__global__ __launch_bounds__(256) void conv_x(const float4* __restrict__ in,
                                              u16* __restrict__ outp, int n4)
{
    for (int i = blockIdx.x * 256 + threadIdx.x; i < n4; i += gridDim.x * 256) {
        float4 v = in[i];
        union { u16 s[4]; uint2 u; } o;
        o.s[0] = f2bf(v.x); o.s[1] = f2bf(v.y); o.s[2] = f2bf(v.z); o.s[3] = f2bf(v.w);
        ((uint2*)outp)[i] = o.u;
    }
}

// ---- bf16 GEMM, 2-phase double-buffered prefetch (T3 minimal recipe) ----
// C[m][n] = sum_k A[m][k]*Bt[n][k] (+bias). 128^2 tile, BK=32, 4 waves.
// STAGE(t+1) issued BEFORE compute of t; counted vmcnt(4) (never 0 mid-loop);
// raw s_barrier x2 per K-step. T2 XOR slot-swizzle kept (conflict-free reads).
template<bool F32OUT>
__global__ __launch_bounds__(256) void gemm_bt(const u16* __restrict__ A,
                                               const u16* __restrict__ Bt,
                                               const float* __restrict__ bias,
                                               void* __restrict__ Cout)
{
    __shared__ u16 lds2[2][2][4096];   // [buf][A=0/B=1][128 rows x 32 bf16]
    const int tid  = threadIdx.x;
    const int lane = tid & 63;
    const int wvb  = tid & ~63;              // wave*64
    const int wm   = ((tid >> 7) & 1) * 64;  // wave row block
    const int wn   = ((tid >> 6) & 1) * 64;  // wave col block
    // XCD-chunked bijective swizzle: 2688 = 8 * 336
    const int wg = blockIdx.x;
    const int id = (wg & 7) * 336 + (wg >> 3);
    const int tn = (id % 6) * 128;
    const int tm = (id / 6) * 128;

    f32x4 acc[4][4] = {};

    const int lr = lane & 15;
    // read-side swizzle: logical slot = lane>>4, physical = l ^ ((row>>1)&3)
    const int lk = (((lane >> 4) ^ ((lr >> 1) & 3)) << 3);

    // staging: thread covers rows row0 and row0+64, pre-swizzled k-chunk kc0
    const int row0 = tid >> 2;
    const int kc0  = (((tid & 3) ^ ((tid >> 3) & 3)) << 3);
    const u16* aSrc = A  + (size_t)(tm + row0) * KD + kc0;
    const u16* bSrc = Bt + (size_t)(tn + row0) * KD + kc0;

    #define STAGE(b, ks_) { const int k0 = (ks_) * 32;                      \
        async16(aSrc + k0,                  &lds2[b][0][wvb * 8]);          \
        async16(aSrc + (size_t)64 * KD + k0, &lds2[b][0][(256 + wvb) * 8]); \
        async16(bSrc + k0,                  &lds2[b][1][wvb * 8]);          \
        async16(bSrc + (size_t)64 * KD + k0, &lds2[b][1][(256 + wvb) * 8]); }

    STAGE(0, 0);

    #pragma unroll 2
    for (int ks = 0; ks < KD / 32; ++ks) {
        const int cur = ks & 1;
        if (ks + 1 < KD / 32) {
            STAGE(cur ^ 1, ks + 1);                         // prefetch next
            asm volatile("s_waitcnt vmcnt(4)" ::: "memory"); // oldest 4 = buf cur
        } else {
            asm volatile("s_waitcnt vmcnt(0)" ::: "memory");
        }
        __builtin_amdgcn_s_barrier();
        asm volatile("" ::: "memory");

        const u16* As = lds2[cur][0];
        const u16* Bs = lds2[cur][1];
        bf16x8 af[4], bf[4];
        #pragma unroll
        for (int mi = 0; mi < 4; ++mi)
            af[mi] = *(const bf16x8*)&As[(wm + mi * 16 + lr) * 32 + lk];
        #pragma unroll
        for (int ni = 0; ni < 4; ++ni)
            bf[ni] = *(const bf16x8*)&Bs[(wn + ni * 16 + lr) * 32 + lk];
        #pragma unroll
        for (int mi = 0; mi < 4; ++mi)
            #pragma unroll
            for (int ni = 0; ni < 4; ++ni)
                acc[mi][ni] = __builtin_amdgcn_mfma_f32_16x16x32_bf16(
                    af[mi], bf[ni], acc[mi][ni], 0, 0, 0);

        if (ks + 1 < KD / 32) {        // protect buf cur^... from next STAGE
            asm volatile("" ::: "memory");
            __builtin_amdgcn_s_barrier();
        }
    }
    #undef STAGE

    // epilogue: C/D layout col=lane&15, row=(lane>>4)*4+reg
    const int lr4 = (lane >> 4) << 2;
    #pragma unroll
    for (int ni = 0; ni < 4; ++ni) {
        int col = tn + wn + ni * 16 + lr;
        float bv = bias ? bias[col] : 0.0f;
        #pragma unroll
        for (int mi = 0; mi < 4; ++mi) {
            int rowb = tm + wm + mi * 16 + lr4;
            #pragma unroll
            for (int r = 0; r < 4; ++r) {
                float v = acc[mi][ni][r] + bv;
                if (F32OUT)
                    ((float*)Cout)[(size_t)(rowb + r) * ND + col] = v;
                else
                    ((u16*)Cout)[(size_t)(rowb + r) * ND + col] = f2bf(v);
            }
        }
    }
}

// ---- fused GAT attention per batch: ei/ej from staged Wh, softmax, mix, ELU ----
// LDS-staged (safe when Xout aliases Wh).
template<bool ELU>
__global__ __launch_bounds__(256) void gat_mix(const u16* __restrict__ Wh,
                                               const float* __restrict__ adj,
                                               const float* __restrict__ avec,
                                               float* __restrict__ attn_out,
                                               u16* __restrict__ Xout)
{
    __shared__ u16 wh[14 * 768];
    __shared__ float s_ei[14], s_ej[14];
    __shared__ float s_attn[196];
    const int b = blockIdx.x;
    const int tid = threadIdx.x;
    const u16* whb = Wh + (size_t)b * 10752;

    for (int c = tid; c < 1344; c += 256)
        ((uint4*)wh)[c] = ((const uint4*)whb)[c];
    __syncthreads();

    // ei/ej: 14 rows x 16 lanes, each lane sums 6 chunks of 8, 4-step shuffle
    if (tid < 224) {
        const int i = tid >> 4, l = tid & 15;
        float ai = 0.f, aj = 0.f;
        #pragma unroll
        for (int c = 0; c < 6; ++c) {
            int d = c * 128 + l * 8;
            u16x8 v  = *(const u16x8*)&wh[i * 768 + d];
            float4 x0 = *(const float4*)&avec[d];
            float4 x1 = *(const float4*)&avec[d + 4];
            float4 y0 = *(const float4*)&avec[768 + d];
            float4 y1 = *(const float4*)&avec[768 + d + 4];
            float w0 = bf2f(v[0]), w1 = bf2f(v[1]), w2 = bf2f(v[2]), w3 = bf2f(v[3]);
            float w4 = bf2f(v[4]), w5 = bf2f(v[5]), w6 = bf2f(v[6]), w7 = bf2f(v[7]);
            ai += w0*x0.x + w1*x0.y + w2*x0.z + w3*x0.w + w4*x1.x + w5*x1.y + w6*x1.z + w7*x1.w;
            aj += w0*y0.x + w1*y0.y + w2*y0.z + w3*y0.w + w4*y1.x + w5*y1.y + w6*y1.z + w7*y1.w;
        }
        #pragma unroll
        for (int off = 8; off; off >>= 1) {
            ai += __shfl_xor(ai, off);
            aj += __shfl_xor(aj, off);
        }
        if (l == 0) { s_ei[i] = ai; s_ej[i] = aj; }
    }
    __syncthreads();

    // masked softmax over j per row i (N=14, fp32)
    if (tid < 14) {
        const int i = tid;
        float e[14];
        float mx = -3.0e38f;
        #pragma unroll
        for (int j = 0; j < 14; ++j) {
            float ev = (adj[(size_t)b * 196 + i * 14 + j] > 0.f) ? (s_ei[i] + s_ej[j]) : -1.0e30f;
            e[j] = ev; mx = fmaxf(mx, ev);
        }
        float sum = 0.f;
        #pragma unroll
        for (int j = 0; j < 14; ++j) { float pp = __expf(e[j] - mx); e[j] = pp; sum += pp; }
        float inv = 1.0f / sum;
        #pragma unroll
        for (int j = 0; j < 14; ++j) s_attn[i * 14 + j] = e[j] * inv;
    }
    __syncthreads();

    if (tid < 196) attn_out[(size_t)b * 196 + tid] = s_attn[tid];

    // mix: h[i,d] = sum_j attn[i,j]*Wh[j,d]; opt ELU; write bf16 (16 elems/item)
    for (int pp = tid; pp < 14 * 48; pp += 256) {
        const int i  = pp / 48;
        const int d0 = (pp % 48) * 16;
        float acc[16] = {};
        #pragma unroll
        for (int j = 0; j < 14; ++j) {
            float aw = s_attn[i * 14 + j];
            u16x8 wv0 = *(const u16x8*)&wh[j * 768 + d0];
            u16x8 wv1 = *(const u16x8*)&wh[j * 768 + d0 + 8];
            #pragma unroll
            for (int qq = 0; qq < 8; ++qq) {
                acc[qq]     += aw * bf2f(wv0[qq]);
                acc[8 + qq] += aw * bf2f(wv1[qq]);
            }
        }
        union { u16 s[16]; uint4 u[2]; } o;
        #pragma unroll
        for (int qq = 0; qq < 16; ++qq) {
            float v = acc[qq];
            if (ELU && v < 0.f) v = __expf(v) - 1.0f;
            o.s[qq] = f2bf(v);
        }
        *(uint4*)&Xout[(size_t)b * 10752 + i * 768 + d0]     = o.u[0];
        *(uint4*)&Xout[(size_t)b * 10752 + i * 768 + d0 + 8] = o.u[1];
    }
}

extern "C" void kernel_launch(void* const* d_in, const int* in_sizes, int n_in,
                              void* d_out, int out_size, void* d_ws, size_t ws_size,
                              hipStream_t stream)
{
    const float* features = (const float*)d_in[0];
    const float* adj      = (const float*)d_in[1];
    const float* W_emb    = (const float*)d_in[2];
    const float* b_emb    = (const float*)d_in[3];
    const float* gat_W    = (const float*)d_in[4];
    const float* gat_a    = (const float*)d_in[5];
    const float* W_out    = (const float*)d_in[6];
    const float* b_out    = (const float*)d_in[7];
    float* out = (float*)d_out;

    // ws: Wh (bf16 57344x768) | Wt (5 transposed bf16 mats)
    u16* Wh = (u16*)d_ws;
    u16* Wt = Wh + 44040192;
    // out-region as two bf16 x ping-pong halves until the final GEMM
    u16* H0 = (u16*)d_out;
    u16* H1 = H0 + 44040192;
    float* attn0 = out + 44040192;
    float* attn1 = attn0 + 802816;
    float* attn2 = attn1 + 802816;

    conv_w<<<dim3(720), 256, 0, stream>>>(W_emb, gat_W, W_out, Wt);
    conv_x<<<dim3(4096), 256, 0, stream>>>((const float4*)features, H0, 11010048);

    dim3 gg(2688);
    // x0 = features @ W_emb + b_emb
    gemm_bt<false><<<gg, 256, 0, stream>>>(H0, Wt, b_emb, H1);
    // layer 0
    gemm_bt<false><<<gg, 256, 0, stream>>>(H1, Wt + 589824, nullptr, Wh);
    gat_mix<true><<<dim3(4096), 256, 0, stream>>>(Wh, adj, gat_a, attn0, H0);
    // layer 1
    gemm_bt<false><<<gg, 256, 0, stream>>>(H0, Wt + 2 * 589824, nullptr, Wh);
    gat_mix<true><<<dim3(4096), 256, 0, stream>>>(Wh, adj, gat_a + 1536, attn1, H1);
    // layer 2 (no ELU; x3 in-place over Wh -> staged kernel is safe)
    gemm_bt<false><<<gg, 256, 0, stream>>>(H1, Wt + 3 * 589824, nullptr, Wh);
    gat_mix<false><<<dim3(4096), 256, 0, stream>>>(Wh, adj, gat_a + 3072, attn2, Wh);
    // out = x3 @ W_out + b_out (fp32)
    gemm_bt<true><<<gg, 256, 0, stream>>>(Wh, Wt + 4 * 589824, b_out, (void*)out);
}